// Round 6
// baseline (21.148 us; speedup 1.0000x reference)
//
#include <hip/hip_runtime.h>

#define NUM_EMBEDDINGS 50000
#define EMBEDDING_DIM  1024
#define N_CENTROIDS    256
#define N_BLOCKS       128    // EMBEDDING_DIM / 8
#define N_TOKENS       16384  // BATCH * SEQ
#define N_PARTS        8      // one per XCD
#define BLKS_PER_PART  (N_BLOCKS / N_PARTS)   // 16
#define T_PER_THREAD   8      // ILP: 8 independent gather->store chains/thread

typedef float f32x4 __attribute__((ext_vector_type(4)));

// XCD-sliced gather + nt stores + 8-way ILP.
//
//   part = bid & 7  -> fixed XCD; its L2 caches only blks [16p,16p+16) of
//                      assignments (3.2 MB < 4 MB), protected by nt stores.
//   Each 256-thread block covers 64 tokens for its part:
//     tgrp = tid>>5 (8 groups of 32 lanes), thread handles tokens
//     tb + 8k, k=0..7 where tb = (bid>>3)*64 + tgrp.
//   Per thread: 8 independent chains id->code->centroid->store, issued in
//   batched unrolled loops so 8 loads of each class are in flight at once
//   (R5 was one chain/thread = 3 serial L2 latencies per 16 B store).
__global__ __launch_bounds__(256) void pq_embed_ilp_kernel(
    const float* __restrict__ centroids,     // [256][8]
    const int*   __restrict__ assignments,   // [128][50000]
    const int*   __restrict__ input_ids,     // [16384]
    float*       __restrict__ out)           // [16384][1024]
{
    const int part  = blockIdx.x & (N_PARTS - 1);
    const int group = blockIdx.x >> 3;

    const int tid  = threadIdx.x;
    const int tgrp = tid >> 5;
    const int lane = tid & 31;

    const int tb   = group * (8 * T_PER_THREAD) + tgrp;   // + 8k, k=0..7
    const int blk  = part * BLKS_PER_PART + (lane >> 1);
    const int half = lane & 1;

    const int* __restrict__ arow = assignments + (size_t)blk * NUM_EMBEDDINGS;
    const f32x4* __restrict__ c4 = reinterpret_cast<const f32x4*>(centroids);
    f32x4* __restrict__ o4       = reinterpret_cast<f32x4*>(out);

    int id[T_PER_THREAD];
    #pragma unroll
    for (int k = 0; k < T_PER_THREAD; ++k)
        id[k] = input_ids[tb + 8 * k];

    int code[T_PER_THREAD];
    #pragma unroll
    for (int k = 0; k < T_PER_THREAD; ++k)
        code[k] = arow[id[k]];

    f32x4 v[T_PER_THREAD];
    #pragma unroll
    for (int k = 0; k < T_PER_THREAD; ++k)
        v[k] = c4[(code[k] << 1) + half];

    #pragma unroll
    for (int k = 0; k < T_PER_THREAD; ++k) {
        f32x4* dst = o4 + (size_t)(tb + 8 * k) * (EMBEDDING_DIM / 4) + part * 32 + lane;
        __builtin_nontemporal_store(v[k], dst);
    }
}

extern "C" void kernel_launch(void* const* d_in, const int* in_sizes, int n_in,
                              void* d_out, int out_size, void* d_ws, size_t ws_size,
                              hipStream_t stream) {
    const float* centroids   = (const float*)d_in[0];
    const int*   assignments = (const int*)d_in[1];
    const int*   input_ids   = (const int*)d_in[2];
    float*       out         = (float*)d_out;

    // 16384 tokens / 64 tokens-per-block * 8 parts = 2048 blocks
    dim3 grid((N_TOKENS / (8 * T_PER_THREAD)) * N_PARTS);
    dim3 block(256);
    pq_embed_ilp_kernel<<<grid, block, 0, stream>>>(centroids, assignments, input_ids, out);
}

// Round 7
// 20.493 us; speedup vs baseline: 1.0320x; 1.0320x over previous
//
#include <hip/hip_runtime.h>

#define NUM_EMBEDDINGS 50000
#define EMBEDDING_DIM  1024
#define N_CENTROIDS    256
#define N_BLOCKS       128    // EMBEDDING_DIM / 8
#define N_TOKENS       16384  // BATCH * SEQ
#define N_PARTS        8      // one per XCD
#define BLKS_PER_PART  (N_BLOCKS / N_PARTS)        // 16
#define TOKENS_PER_WG  8      // 256 threads = 8 groups of 32 lanes

typedef float f32x4 __attribute__((ext_vector_type(4)));

// R5 structure (XCD-sliced code reads + nt stores) + LDS-staged centroids.
//
//   part = bid & 7  -> fixed XCD; its L2 caches only blks [16p,16p+16) of
//                      assignments (3.2 MB < 4 MB), protected by nt stores.
//   centroids (8 KB) staged in LDS once per block: the random per-lane
//   16 B centroid lookup becomes ds_read_b128 (bank-parallel, ~24 cy/wave)
//   instead of ~40 serialized L1-line transactions per wave (R5's limiter).
//
// Thread (tgrp = tid>>5, lane = tid&31):
//   token = (bid>>3)*8 + tgrp
//   blk   = 16*part + (lane>>1) ; half = lane&1
//   code  = assignments[blk*NUM_EMBEDDINGS + id]     (4 B, XCD-local L2)
//   out float4 #(token*256 + part*32 + lane) = lds_centroid[code*2 + half]
__global__ __launch_bounds__(256) void pq_embed_lds_kernel(
    const float* __restrict__ centroids,     // [256][8]
    const int*   __restrict__ assignments,   // [128][50000]
    const int*   __restrict__ input_ids,     // [16384]
    float*       __restrict__ out)           // [16384][1024]
{
    __shared__ f32x4 c_lds[N_CENTROIDS * 2];   // 512 float4 = 8 KB

    const int tid = threadIdx.x;

    // Stage centroid table (coalesced: 2 float4 per thread).
    {
        const f32x4* __restrict__ cg = reinterpret_cast<const f32x4*>(centroids);
        c_lds[tid]       = cg[tid];
        c_lds[tid + 256] = cg[tid + 256];
    }
    __syncthreads();

    const int part  = blockIdx.x & (N_PARTS - 1);
    const int group = blockIdx.x >> 3;

    const int tgrp = tid >> 5;
    const int lane = tid & 31;

    const int token = group * TOKENS_PER_WG + tgrp;
    const int id    = input_ids[token];

    const int blk  = part * BLKS_PER_PART + (lane >> 1);
    const int half = lane & 1;

    const int code = assignments[blk * NUM_EMBEDDINGS + id];

    const f32x4 v = c_lds[(code << 1) + half];

    f32x4* dst = reinterpret_cast<f32x4*>(out) +
                 (size_t)token * (EMBEDDING_DIM / 4) + part * 32 + lane;
    __builtin_nontemporal_store(v, dst);
}

extern "C" void kernel_launch(void* const* d_in, const int* in_sizes, int n_in,
                              void* d_out, int out_size, void* d_ws, size_t ws_size,
                              hipStream_t stream) {
    const float* centroids   = (const float*)d_in[0];
    const int*   assignments = (const int*)d_in[1];
    const int*   input_ids   = (const int*)d_in[2];
    float*       out         = (float*)d_out;

    dim3 grid((N_TOKENS / TOKENS_PER_WG) * N_PARTS);  // 16384
    dim3 block(256);
    pq_embed_lds_kernel<<<grid, block, 0, stream>>>(centroids, assignments, input_ids, out);
}